// Round 6
// baseline (462.832 us; speedup 1.0000x reference)
//
#include <hip/hip_runtime.h>
#include <hip/hip_bf16.h>

// Problem constants
#define NN 8192
#define FF 128
#define DD 128
#define HH 2
#define ALPHA 0.3f
#define MAXNNZ 1024

typedef float vfloat4 __attribute__((ext_vector_type(4)));

// ---------------------------------------------------------------------------
// Kernel P (fused prep): grid (256, H), 256 threads.
// Block (rb, h) with rows r0 = rb*32 .. +31:
//   1. stage x rows into LDS (Al), compute cvec[2][128] = Wmap[h]@{a1w,a2w}
//   2. sa1/sa2 for its 32 rows (head h) from Al . cvec
//   3. value[h] tile = Al @ kernel[h]  (fp32 acc, bf16 store)
//   4. fused colsum partial -> atomicAdd
// ---------------------------------------------------------------------------
__global__ __launch_bounds__(256) void prep_kernel(
    const float* __restrict__ x, const float* __restrict__ kern,
    const float* __restrict__ Wmap, const float* __restrict__ a1w,
    const float* __restrict__ a2w, const float* __restrict__ a1b,
    const float* __restrict__ a2b, unsigned short* __restrict__ value_bf,
    float* __restrict__ colsum, float* __restrict__ sa1, float* __restrict__ sa2) {
  int h = blockIdx.y;
  int row0 = blockIdx.x * 32;
  __shared__ float Bl[64 * 128];    // 32 KB
  __shared__ float Al[32 * 129];    // 16.5 KB
  __shared__ float cvec[2][128];    // 1 KB
  const float4* Bg4 = (const float4*)(kern + (size_t)h * FF * DD);
  const float4* Ag4 = (const float4*)(x + (size_t)row0 * FF);
  float4* Bl4 = (float4*)Bl;
  int tid = threadIdx.x;

  // ---- stage A: 32 rows x 128 cols = 1024 float4 ----
  #pragma unroll
  for (int q = 0; q < 4; q++) {
    int idx = q * 256 + tid;        // 0..1023
    int r = idx >> 5, c4 = idx & 31;
    float4 g = Ag4[idx];
    Al[r * 129 + c4 * 4 + 0] = g.x;
    Al[r * 129 + c4 * 4 + 1] = g.y;
    Al[r * 129 + c4 * 4 + 2] = g.z;
    Al[r * 129 + c4 * 4 + 3] = g.w;
  }

  // ---- c vectors: thread t -> (which = t>>7, f = t&127) ----
  {
    int which = tid >> 7, f = tid & 127;
    const float4* w4 = (const float4*)(Wmap + ((size_t)h * FF + f) * DD);
    const float4* av4 = (const float4*)((which ? a2w : a1w) + (size_t)h * DD);
    float s = 0.f;
    #pragma unroll 8
    for (int dq = 0; dq < 32; dq++) {
      float4 w = w4[dq];
      float4 a = av4[dq];
      s += w.x * a.x + w.y * a.y + w.z * a.z + w.w * a.w;
    }
    cvec[which][f] = s;
  }
  __syncthreads();

  // ---- sa for this block's 32 rows, head h (threads 0..63) ----
  if (tid < 64) {
    int r = tid & 31, type = tid >> 5;
    const float* cv = cvec[type];
    float s = 0.f;
    #pragma unroll 8
    for (int f = 0; f < 128; f++) s += Al[r * 129 + f] * cv[f];
    float b = type ? a2b[h] : a1b[h];
    float* dst = type ? sa2 : sa1;
    dst[(size_t)h * NN + row0 + r] = s + b;
  }

  // ---- GEMM: thread tile 4 rows x 4 cols ----
  int cg = tid & 31;                // cols cg*4..cg*4+3
  int rg = tid >> 5;                // rows rg, rg+8, rg+16, rg+24
  float4 acc[4];
  #pragma unroll
  for (int m = 0; m < 4; m++) acc[m] = make_float4(0.f, 0.f, 0.f, 0.f);

  for (int kp = 0; kp < 2; kp++) {
    __syncthreads();
    #pragma unroll
    for (int q = 0; q < 8; q++)
      Bl4[q * 256 + tid] = Bg4[kp * 2048 + q * 256 + tid];
    __syncthreads();
    for (int k2 = 0; k2 < 64; k2++) {
      int k = kp * 64 + k2;
      float4 bv = *(const float4*)&Bl[k2 * 128 + cg * 4];
      #pragma unroll
      for (int m = 0; m < 4; m++) {
        float av = Al[(rg + m * 8) * 129 + k];
        acc[m].x += av * bv.x;
        acc[m].y += av * bv.y;
        acc[m].z += av * bv.z;
        acc[m].w += av * bv.w;
      }
    }
  }

  // ---- store bf16 value rows ----
  #pragma unroll
  for (int m = 0; m < 4; m++) {
    int r = row0 + rg + m * 8;
    ushort4 pk;
    __hip_bfloat16 b0 = __float2bfloat16(acc[m].x);
    __hip_bfloat16 b1 = __float2bfloat16(acc[m].y);
    __hip_bfloat16 b2 = __float2bfloat16(acc[m].z);
    __hip_bfloat16 b3 = __float2bfloat16(acc[m].w);
    pk.x = *(unsigned short*)&b0;
    pk.y = *(unsigned short*)&b1;
    pk.z = *(unsigned short*)&b2;
    pk.w = *(unsigned short*)&b3;
    *(ushort4*)&value_bf[((size_t)h * NN + r) * DD + cg * 4] = pk;
  }

  // ---- fused colsum: per-thread column partials -> LDS -> atomicAdd ----
  float4 cp;
  cp.x = acc[0].x + acc[1].x + acc[2].x + acc[3].x;
  cp.y = acc[0].y + acc[1].y + acc[2].y + acc[3].y;
  cp.z = acc[0].z + acc[1].z + acc[2].z + acc[3].z;
  cp.w = acc[0].w + acc[1].w + acc[2].w + acc[3].w;
  __syncthreads();                  // done reading Al; reuse as colred[8][128]
  float* colred = Al;
  *(float4*)&colred[rg * 128 + cg * 4] = cp;
  __syncthreads();
  if (rg == 0) {                    // tid 0..31, each owns 4 columns
    #pragma unroll
    for (int c = 0; c < 4; c++) {
      int col = cg * 4 + c;
      float s = 0.f;
      #pragma unroll
      for (int rr = 0; rr < 8; rr++) s += colred[rr * 128 + col];
      atomicAdd(&colsum[h * DD + col], s);
    }
  }
}

// ---------------------------------------------------------------------------
// Kernel E: main sparse-attention kernel. One block (256 thr) per row i.
//   Phase A : hoisted nt float4 scan; rare-branch atomic compaction into LDS
//             (idxbuf order is arbitrary — sums are order-invariant).
//   Phase B1: one thread per edge: em1 = exp(leaky(s)) - 1 (both heads).
//   Phase B2: 4 waves = 2 heads x 2 edge-strides; ushort2 (2 d-vals) per
//             lane per edge; halves combined through LDS in the epilogue.
// ---------------------------------------------------------------------------
__global__ __launch_bounds__(256) void gat_main(
    const float* __restrict__ adj, const float* __restrict__ sa1,
    const float* __restrict__ sa2, const unsigned short* __restrict__ value_bf,
    const float* __restrict__ colsum, const float* __restrict__ bias,
    float* __restrict__ out) {
  int i = blockIdx.x;
  __shared__ int idxbuf[MAXNNZ];
  __shared__ float em1buf[HH][MAXNNZ];
  __shared__ int cnt;
  __shared__ float sume_sh[HH];
  __shared__ float wred[4][HH];
  __shared__ float red[4][128];
  int t = threadIdx.x;
  int lane = t & 63;
  int wave = t >> 6;
  if (t == 0) cnt = 0;
  __syncthreads();

  // ---- Phase A: scan adj row, compact nonzero cols (order-free) ----
  const vfloat4* arow = (const vfloat4*)(adj + (size_t)i * NN);
  vfloat4 av[8];
  #pragma unroll
  for (int q = 0; q < 8; q++)
    av[q] = __builtin_nontemporal_load(&arow[q * 256 + t]);
  #pragma unroll
  for (int q = 0; q < 8; q++) {
    vfloat4 a = av[q];
    int nz4 = (a[0] != 0.f) + (a[1] != 0.f) + (a[2] != 0.f) + (a[3] != 0.f);
    if (nz4) {
      int p = atomicAdd(&cnt, nz4);
      int j0 = (q * 256 + t) * 4;
      #pragma unroll
      for (int c = 0; c < 4; c++) {
        if (a[c] != 0.f) {
          if (p < MAXNNZ) idxbuf[p] = j0 + c;
          p++;
        }
      }
    }
  }
  __syncthreads();
  int count = min(cnt, MAXNNZ);

  // ---- Phase B1: per-edge scores ----
  float s10 = sa1[i];               // head 0 row score
  float s11 = sa1[NN + i];          // head 1 row score
  float l0 = 0.f, l1 = 0.f;         // partial sums of (e-1)
  for (int k = t; k < count; k += 256) {
    int j = idxbuf[k];
    float w0 = s10 + sa2[j];
    float w1 = s11 + sa2[NN + j];
    w0 = (w0 >= 0.f) ? w0 : ALPHA * w0;
    w1 = (w1 >= 0.f) ? w1 : ALPHA * w1;
    float e0 = __expf(w0) - 1.f;
    float e1 = __expf(w1) - 1.f;
    em1buf[0][k] = e0;
    em1buf[1][k] = e1;
    l0 += e0;
    l1 += e1;
  }
  #pragma unroll
  for (int o = 32; o > 0; o >>= 1) {
    l0 += __shfl_down(l0, o);
    l1 += __shfl_down(l1, o);
  }
  if (lane == 0) { wred[wave][0] = l0; wred[wave][1] = l1; }
  __syncthreads();
  if (t == 0) {
    sume_sh[0] = wred[0][0] + wred[1][0] + wred[2][0] + wred[3][0];
    sume_sh[1] = wred[0][1] + wred[1][1] + wred[2][1] + wred[3][1];
  }

  // ---- Phase B2: weighted gather, ushort2 per lane per edge ----
  int h = wave >> 1;                // head
  int half = wave & 1;              // edge stride offset
  int d0 = lane * 2;                // this lane's d pair
  const unsigned short* val = value_bf + (size_t)h * NN * DD + d0;
  const float* eb = em1buf[h];
  float ax = 0.f, ay = 0.f;
  for (int k = half; k < count; k += 2) {
    int j = idxbuf[k];
    unsigned int u = *(const unsigned int*)&val[(size_t)j * DD];
    float e = eb[k];
    unsigned short ulo = (unsigned short)(u & 0xffff);
    unsigned short uhi = (unsigned short)(u >> 16);
    __hip_bfloat16 blo = *(__hip_bfloat16*)&ulo;
    __hip_bfloat16 bhi = *(__hip_bfloat16*)&uhi;
    ax += e * __bfloat162float(blo);
    ay += e * __bfloat162float(bhi);
  }
  red[wave][d0] = ax;
  red[wave][d0 + 1] = ay;
  __syncthreads();

  // ---- epilogue: threads 0..127, one per output d ----
  if (t < 128) {
    int d = t;
    float acc0 = red[0][d] + red[1][d];
    float acc1 = red[2][d] + red[3][d];
    float denom0 = (float)NN + sume_sh[0];
    float denom1 = (float)NN + sume_sh[1];
    float b0 = bias[(size_t)i * DD + d];
    float b1 = bias[(size_t)NN * DD + (size_t)i * DD + d];
    float r0 = (colsum[d] + acc0) / denom0 + b0;
    float r1 = (colsum[DD + d] + acc1) / denom1 + b1;
    out[(size_t)i * DD + d] = 0.5f * (r0 + r1);
  }
}

// ---------------------------------------------------------------------------
// Launch
// ---------------------------------------------------------------------------
extern "C" void kernel_launch(void* const* d_in, const int* in_sizes, int n_in,
                              void* d_out, int out_size, void* d_ws, size_t ws_size,
                              hipStream_t stream) {
  const float* x    = (const float*)d_in[0];
  const float* adj  = (const float*)d_in[1];
  const float* Wmap = (const float*)d_in[2];
  const float* a1w  = (const float*)d_in[3];
  const float* a1b  = (const float*)d_in[4];
  const float* a2w  = (const float*)d_in[5];
  const float* a2b  = (const float*)d_in[6];
  const float* kern = (const float*)d_in[7];
  const float* bias = (const float*)d_in[8];
  float* out = (float*)d_out;
  float* ws  = (float*)d_ws;

  // workspace layout (floats)
  float* sa1    = ws;            // 16384
  float* sa2    = ws + 16384;    // 16384
  float* colsum = ws + 32768;    // 256
  unsigned short* value_bf = (unsigned short*)(ws + 33024);  // 2*8192*128 bf16

  (void)hipMemsetAsync(colsum, 0, HH * DD * sizeof(float), stream);
  prep_kernel<<<dim3(NN / 32, HH), 256, 0, stream>>>(
      x, kern, Wmap, a1w, a2w, a1b, a2b, value_bf, colsum, sa1, sa2);
  gat_main<<<NN, 256, 0, stream>>>(adj, sa1, sa2, value_bf, colsum, bias, out);
}